// Round 1
// baseline (1393.596 us; speedup 1.0000x reference)
//
#include <hip/hip_runtime.h>
#include <hip/hip_bf16.h>
#include <math.h>

#define N_NODES 50000
#define N_EDGES 800000
#define NUM_GRAPHS 500
#define F_IN 128
#define HID 256
#define NCLS 10

// ---------------- GEMM: C[N,M] = A[N,K] @ B[K,M] (+ bias) ----------------
#define BM 64
#define BN 64
#define BK 16

__global__ __launch_bounds__(256) void gemm_bias(
    const float* __restrict__ A, const float* __restrict__ B,
    const float* __restrict__ bias, float* __restrict__ C,
    int N, int K, int M) {
  __shared__ float As[BK][BM + 1];
  __shared__ float Bs[BK][BN];
  const int row0 = blockIdx.x * BM;
  const int col0 = blockIdx.y * BN;
  const int t = threadIdx.x;
  const int tx = t & 15, ty = t >> 4;
  float acc[4][4] = {};
  for (int k0 = 0; k0 < K; k0 += BK) {
#pragma unroll
    for (int i = 0; i < 4; ++i) {
      int idx = t + i * 256;
      int m = idx >> 4, k = idx & 15;
      int gr = row0 + m;
      As[k][m] = (gr < N) ? A[(size_t)gr * K + k0 + k] : 0.f;
    }
#pragma unroll
    for (int i = 0; i < 4; ++i) {
      int idx = t + i * 256;
      int k = idx >> 6, n = idx & 63;
      Bs[k][n] = B[(size_t)(k0 + k) * M + col0 + n];
    }
    __syncthreads();
#pragma unroll
    for (int k = 0; k < BK; ++k) {
      float a[4], b[4];
#pragma unroll
      for (int i = 0; i < 4; ++i) a[i] = As[k][ty * 4 + i];
#pragma unroll
      for (int j = 0; j < 4; ++j) b[j] = Bs[k][tx * 4 + j];
#pragma unroll
      for (int i = 0; i < 4; ++i)
#pragma unroll
        for (int j = 0; j < 4; ++j) acc[i][j] += a[i] * b[j];
    }
    __syncthreads();
  }
#pragma unroll
  for (int i = 0; i < 4; ++i) {
    int gr = row0 + ty * 4 + i;
    if (gr < N) {
#pragma unroll
      for (int j = 0; j < 4; ++j) {
        int gc = col0 + tx * 4 + j;
        float v = acc[i][j];
        if (bias) v += bias[gc];
        C[(size_t)gr * M + gc] = v;
      }
    }
  }
}

// ---------------- degree / normalization ----------------
__global__ __launch_bounds__(256) void deg_init(float* deg, int N) {
  int i = blockIdx.x * 256 + threadIdx.x;
  if (i < N) deg[i] = 1.0f;  // self-loop weight
}

__global__ __launch_bounds__(256) void deg_accum(
    const int* __restrict__ src, const int* __restrict__ dst,
    const float* __restrict__ ew, float* deg, int* cnt, int E) {
  int e = blockIdx.x * 256 + threadIdx.x;
  if (e < E) {
    int d = dst[e];
    atomicAdd(&deg[d], ew[e]);
    atomicAdd(&cnt[d], 1);
  }
  (void)src;
}

__global__ __launch_bounds__(256) void dinv_k(const float* deg, float* dinv, int N) {
  int i = blockIdx.x * 256 + threadIdx.x;
  if (i < N) {
    float d = deg[i];
    dinv[i] = (d > 0.f) ? rsqrtf(fmaxf(d, 1e-12f)) : 0.f;
  }
}

// exclusive scan of cnt[0..n) -> row_ptr[0..n], single block 1024 threads
__global__ __launch_bounds__(1024) void scan_excl(const int* __restrict__ cnt,
                                                  int* __restrict__ row_ptr, int n) {
  __shared__ int s[1024];
  __shared__ int carry;
  if (threadIdx.x == 0) carry = 0;
  __syncthreads();
  for (int base = 0; base < n; base += 1024) {
    int i = base + threadIdx.x;
    int v = (i < n) ? cnt[i] : 0;
    s[threadIdx.x] = v;
    __syncthreads();
    for (int off = 1; off < 1024; off <<= 1) {
      int t2 = 0;
      if (threadIdx.x >= off) t2 = s[threadIdx.x - off];
      __syncthreads();
      if (threadIdx.x >= off) s[threadIdx.x] += t2;
      __syncthreads();
    }
    int incl = s[threadIdx.x];
    if (i < n) row_ptr[i] = carry + incl - v;
    __syncthreads();
    if (threadIdx.x == 1023) carry += incl;
    __syncthreads();
  }
  if (threadIdx.x == 0) row_ptr[n] = carry;
}

__global__ __launch_bounds__(256) void csr_fill(
    const int* __restrict__ src, const int* __restrict__ dst,
    const float* __restrict__ ew, const float* __restrict__ dinv,
    const int* __restrict__ row_ptr, int* cursor,
    int* __restrict__ csr_src, float* __restrict__ csr_coef, int E) {
  int e = blockIdx.x * 256 + threadIdx.x;
  if (e < E) {
    int s = src[e], d = dst[e];
    int pos = atomicAdd(&cursor[d], 1);
    int idx = row_ptr[d] + pos;
    csr_src[idx] = s;
    csr_coef[idx] = dinv[s] * ew[e] * dinv[d];
  }
}

// ---------------- aggregation + bias + ELU ----------------
__global__ __launch_bounds__(256) void gather_elu(
    const float* __restrict__ hW, const float* __restrict__ dinv,
    const int* __restrict__ row_ptr, const int* __restrict__ csr_src,
    const float* __restrict__ csr_coef, const float* __restrict__ bias,
    float* __restrict__ out) {
  const int n = blockIdx.x;
  const int f = threadIdx.x;  // 256 features
  __shared__ int s_src[64];
  __shared__ float s_c[64];
  const int start = row_ptr[n], end = row_ptr[n + 1];
  float di = dinv[n];
  float acc = di * di * hW[(size_t)n * HID + f];
  for (int base = start; base < end; base += 64) {
    int cnt = min(64, end - base);
    if (threadIdx.x < cnt) {
      s_src[threadIdx.x] = csr_src[base + threadIdx.x];
      s_c[threadIdx.x] = csr_coef[base + threadIdx.x];
    }
    __syncthreads();
    for (int j = 0; j < cnt; ++j)
      acc += s_c[j] * hW[(size_t)s_src[j] * HID + f];
    __syncthreads();
  }
  acc += bias[f];
  out[(size_t)n * HID + f] = (acc > 0.f) ? acc : expm1f(acc);
}

// ---------------- pooling + final linear ----------------
__global__ __launch_bounds__(256) void pool_accum(
    const float* __restrict__ h, const int* __restrict__ batch,
    float* sums, int* cnts) {
  int n = blockIdx.x;
  int f = threadIdx.x;
  int g = batch[n];
  atomicAdd(&sums[(size_t)g * HID + f], h[(size_t)n * HID + f]);
  if (f == 0) atomicAdd(&cnts[g], 1);
}

__global__ __launch_bounds__(256) void final_lin(
    const float* __restrict__ sums, const int* __restrict__ cnts,
    const float* __restrict__ W, const float* __restrict__ b,
    float* __restrict__ out) {
  int g = blockIdx.x;
  __shared__ float part[NCLS * 256];
  int f = threadIdx.x;
  float denom = fmaxf((float)cnts[g], 1.0f);
  float v = sums[(size_t)g * HID + f] / denom;
#pragma unroll
  for (int c = 0; c < NCLS; ++c) part[c * 256 + f] = v * W[f * NCLS + c];
  __syncthreads();
  for (int off = 128; off > 0; off >>= 1) {
    if (f < off) {
#pragma unroll
      for (int c = 0; c < NCLS; ++c) part[c * 256 + f] += part[c * 256 + f + off];
    }
    __syncthreads();
  }
  if (f < NCLS) out[g * NCLS + f] = part[f * 256] + b[f];
}

extern "C" void kernel_launch(void* const* d_in, const int* in_sizes, int n_in,
                              void* d_out, int out_size, void* d_ws, size_t ws_size,
                              hipStream_t stream) {
  const float* x = (const float*)d_in[0];
  const int* ei = (const int*)d_in[1];
  const int* e_src = ei;
  const int* e_dst = ei + N_EDGES;
  const float* ea = (const float*)d_in[2];
  // d_in[3] = edge_type: unused (no per-type parameters in reference)
  const int* batch = (const int*)d_in[4];
  const float* enc1_w = (const float*)d_in[5];
  const float* enc1_b = (const float*)d_in[6];
  const float* enc2_w = (const float*)d_in[7];
  const float* enc2_b = (const float*)d_in[8];
  const float* conv_ws = (const float*)d_in[9];
  const float* conv_bs = (const float*)d_in[10];
  const float* lin1_w = (const float*)d_in[11];
  const float* lin1_b = (const float*)d_in[12];
  float* out = (float*)d_out;

  char* w = (char*)d_ws;
  size_t off = 0;
  auto alloc = [&](size_t bytes) {
    size_t o = off;
    off = (off + bytes + 255) & ~(size_t)255;
    return (void*)(w + o);
  };
  float* bufA = (float*)alloc((size_t)N_NODES * HID * 4);
  float* bufB = (float*)alloc((size_t)N_NODES * HID * 4);
  float* deg = (float*)alloc((size_t)N_NODES * 4);
  float* dinv = (float*)alloc((size_t)N_NODES * 4);
  int* cnt = (int*)alloc((size_t)N_NODES * 4);
  int* row_ptr = (int*)alloc((size_t)(N_NODES + 1) * 4);
  int* cursor = (int*)alloc((size_t)N_NODES * 4);
  int* csr_src = (int*)alloc((size_t)N_EDGES * 4);
  float* csr_coef = (float*)alloc((size_t)N_EDGES * 4);
  float* sums = (float*)alloc((size_t)NUM_GRAPHS * HID * 4);
  int* cnts = (int*)alloc((size_t)NUM_GRAPHS * 4);
  (void)ws_size; (void)in_sizes; (void)n_in; (void)out_size;

  // zero the accumulators we rely on (ws is poisoned, not re-zeroed)
  hipMemsetAsync(cnt, 0, (size_t)N_NODES * 4, stream);
  hipMemsetAsync(cursor, 0, (size_t)N_NODES * 4, stream);
  hipMemsetAsync(sums, 0, (size_t)NUM_GRAPHS * HID * 4, stream);
  hipMemsetAsync(cnts, 0, (size_t)NUM_GRAPHS * 4, stream);

  const int nb_nodes = (N_NODES + 255) / 256;
  const int nb_edges = (N_EDGES + 255) / 256;

  // graph normalization + CSR (independent of h; built once per call)
  deg_init<<<nb_nodes, 256, 0, stream>>>(deg, N_NODES);
  deg_accum<<<nb_edges, 256, 0, stream>>>(e_src, e_dst, ea, deg, cnt, N_EDGES);
  dinv_k<<<nb_nodes, 256, 0, stream>>>(deg, dinv, N_NODES);
  scan_excl<<<1, 1024, 0, stream>>>(cnt, row_ptr, N_NODES);
  csr_fill<<<nb_edges, 256, 0, stream>>>(e_src, e_dst, ea, dinv, row_ptr, cursor,
                                         csr_src, csr_coef, N_EDGES);

  const int gR = (N_NODES + BM - 1) / BM;  // 782

  // encoder: h0 = x@enc1_w + b (N,128) -> bufB ; h1 = h0@enc2_w + b (N,256) -> bufA
  {
    dim3 grid(gR, F_IN / BN);
    gemm_bias<<<grid, 256, 0, stream>>>(x, enc1_w, enc1_b, bufB, N_NODES, F_IN, F_IN);
  }
  {
    dim3 grid(gR, HID / BN);
    gemm_bias<<<grid, 256, 0, stream>>>(bufB, enc2_w, enc2_b, bufA, N_NODES, F_IN, HID);
  }

  // 4 GCN layers: hW = h@W (bufA->bufB); aggregate+bias+ELU (bufB->bufA)
  for (int layer = 0; layer < 4; ++layer) {
    dim3 grid(gR, HID / BN);
    gemm_bias<<<grid, 256, 0, stream>>>(bufA, conv_ws + (size_t)layer * HID * HID,
                                        nullptr, bufB, N_NODES, HID, HID);
    gather_elu<<<N_NODES, 256, 0, stream>>>(bufB, dinv, row_ptr, csr_src, csr_coef,
                                            conv_bs + (size_t)layer * HID, bufA);
  }

  // mean-pool per graph + final linear
  pool_accum<<<N_NODES, 256, 0, stream>>>(bufA, batch, sums, cnts);
  final_lin<<<NUM_GRAPHS, 256, 0, stream>>>(sums, cnts, lin1_w, lin1_b, out);
}

// Round 2
// 1240.718 us; speedup vs baseline: 1.1232x; 1.1232x over previous
//
#include <hip/hip_runtime.h>
#include <hip/hip_bf16.h>
#include <math.h>

#define N_NODES 50000
#define N_EDGES 800000
#define NUM_GRAPHS 500
#define F_IN 128
#define HID 256
#define NCLS 10

// ---------------- GEMM: C[N,M] = A[N,K] @ B[K,M] (+ bias) ----------------
// 128x128 tile, BK=16, 256 threads, 8x8 accum per thread, float4 LDS traffic.
#define TBM 128
#define TBN 128
#define TBK 16

__global__ __launch_bounds__(256) void gemm_bias(
    const float* __restrict__ A, const float* __restrict__ B,
    const float* __restrict__ bias, float* __restrict__ C,
    int N, int K, int M) {
  __shared__ float As[TBK][TBM + 4];  // transposed A tile; +4 keeps 16B align
  __shared__ float Bs[TBK][TBN];
  const int row0 = blockIdx.x * TBM;
  const int col0 = blockIdx.y * TBN;
  const int t = threadIdx.x;
  const int tx = t & 15, ty = t >> 4;
  float acc[8][8] = {};
  for (int k0 = 0; k0 < K; k0 += TBK) {
    // A tile: 128 rows x 16 k, float4 per thread x2, store transposed
#pragma unroll
    for (int i = 0; i < 2; ++i) {
      int idx = t + i * 256;
      int row = idx >> 2;
      int kv = (idx & 3) * 4;
      int gr = row0 + row;
      float4 v = make_float4(0.f, 0.f, 0.f, 0.f);
      if (gr < N) v = *(const float4*)(A + (size_t)gr * K + k0 + kv);
      As[kv + 0][row] = v.x;
      As[kv + 1][row] = v.y;
      As[kv + 2][row] = v.z;
      As[kv + 3][row] = v.w;
    }
    // B tile: 16 k x 128 cols, direct float4
#pragma unroll
    for (int i = 0; i < 2; ++i) {
      int idx = t + i * 256;
      int k = idx >> 5;
      int c = (idx & 31) * 4;
      *(float4*)&Bs[k][c] = *(const float4*)(B + (size_t)(k0 + k) * M + col0 + c);
    }
    __syncthreads();
#pragma unroll
    for (int k = 0; k < TBK; ++k) {
      float a[8], b[8];
      *(float4*)&a[0] = *(const float4*)&As[k][ty * 4];
      *(float4*)&a[4] = *(const float4*)&As[k][ty * 4 + 64];
      *(float4*)&b[0] = *(const float4*)&Bs[k][tx * 4];
      *(float4*)&b[4] = *(const float4*)&Bs[k][tx * 4 + 64];
#pragma unroll
      for (int i = 0; i < 8; ++i)
#pragma unroll
        for (int j = 0; j < 8; ++j) acc[i][j] += a[i] * b[j];
    }
    __syncthreads();
  }
#pragma unroll
  for (int ih = 0; ih < 2; ++ih) {
#pragma unroll
    for (int i = 0; i < 4; ++i) {
      int gr = row0 + ih * 64 + ty * 4 + i;
      if (gr < N) {
#pragma unroll
        for (int jh = 0; jh < 2; ++jh) {
          int gc = col0 + jh * 64 + tx * 4;
          float4 v;
          v.x = acc[ih * 4 + i][jh * 4 + 0];
          v.y = acc[ih * 4 + i][jh * 4 + 1];
          v.z = acc[ih * 4 + i][jh * 4 + 2];
          v.w = acc[ih * 4 + i][jh * 4 + 3];
          if (bias) {
            v.x += bias[gc + 0];
            v.y += bias[gc + 1];
            v.z += bias[gc + 2];
            v.w += bias[gc + 3];
          }
          *(float4*)(C + (size_t)gr * M + gc) = v;
        }
      }
    }
  }
}

// ---------------- degree / normalization ----------------
__global__ __launch_bounds__(256) void deg_init(float* deg, int N) {
  int i = blockIdx.x * 256 + threadIdx.x;
  if (i < N) deg[i] = 1.0f;  // self-loop weight
}

__global__ __launch_bounds__(256) void deg_accum(
    const int* __restrict__ dst, const float* __restrict__ ew,
    float* deg, int* cnt, int E) {
  int e = blockIdx.x * 256 + threadIdx.x;
  if (e < E) {
    int d = dst[e];
    atomicAdd(&deg[d], ew[e]);
    atomicAdd(&cnt[d], 1);
  }
}

__global__ __launch_bounds__(256) void dinv_k(const float* deg, float* dinv, int N) {
  int i = blockIdx.x * 256 + threadIdx.x;
  if (i < N) {
    float d = deg[i];
    dinv[i] = (d > 0.f) ? rsqrtf(fmaxf(d, 1e-12f)) : 0.f;
  }
}

// exclusive scan of cnt[0..n) -> row_ptr[0..n], single block 1024 threads
__global__ __launch_bounds__(1024) void scan_excl(const int* __restrict__ cnt,
                                                  int* __restrict__ row_ptr, int n) {
  __shared__ int s[1024];
  __shared__ int carry;
  if (threadIdx.x == 0) carry = 0;
  __syncthreads();
  for (int base = 0; base < n; base += 1024) {
    int i = base + threadIdx.x;
    int v = (i < n) ? cnt[i] : 0;
    s[threadIdx.x] = v;
    __syncthreads();
    for (int off = 1; off < 1024; off <<= 1) {
      int t2 = 0;
      if (threadIdx.x >= off) t2 = s[threadIdx.x - off];
      __syncthreads();
      if (threadIdx.x >= off) s[threadIdx.x] += t2;
      __syncthreads();
    }
    int incl = s[threadIdx.x];
    if (i < n) row_ptr[i] = carry + incl - v;
    __syncthreads();
    if (threadIdx.x == 1023) carry += incl;
    __syncthreads();
  }
  if (threadIdx.x == 0) row_ptr[n] = carry;
}

__global__ __launch_bounds__(256) void csr_fill(
    const int* __restrict__ src, const int* __restrict__ dst,
    const float* __restrict__ ew, const float* __restrict__ dinv,
    const int* __restrict__ row_ptr, int* cursor,
    int* __restrict__ csr_src, float* __restrict__ csr_coef, int E) {
  int e = blockIdx.x * 256 + threadIdx.x;
  if (e < E) {
    int s = src[e], d = dst[e];
    int pos = atomicAdd(&cursor[d], 1);
    int idx = row_ptr[d] + pos;
    csr_src[idx] = s;
    csr_coef[idx] = dinv[s] * ew[e] * dinv[d];
  }
}

// ---------------- aggregation + bias + ELU: one wave per node ----------------
__global__ __launch_bounds__(256) void gather_elu(
    const float* __restrict__ hW, const float* __restrict__ dinv,
    const int* __restrict__ row_ptr, const int* __restrict__ csr_src,
    const float* __restrict__ csr_coef, const float* __restrict__ bias,
    float* __restrict__ out) {
  const int wave = threadIdx.x >> 6;
  const int lane = threadIdx.x & 63;
  const int n = blockIdx.x * 4 + wave;
  if (n >= N_NODES) return;
  const float4* hw4 = (const float4*)hW;  // 64 float4 per row
  const int start = row_ptr[n], end = row_ptr[n + 1];
  const float di = dinv[n];
  const float cself = di * di;
  float4 h = hw4[(size_t)n * 64 + lane];
  float4 acc;
  acc.x = cself * h.x; acc.y = cself * h.y; acc.z = cself * h.z; acc.w = cself * h.w;
  int e = start;
  for (; e + 2 <= end; e += 2) {
    int s0 = csr_src[e], s1 = csr_src[e + 1];
    float w0 = csr_coef[e], w1 = csr_coef[e + 1];
    float4 v0 = hw4[(size_t)s0 * 64 + lane];
    float4 v1 = hw4[(size_t)s1 * 64 + lane];
    acc.x += w0 * v0.x + w1 * v1.x;
    acc.y += w0 * v0.y + w1 * v1.y;
    acc.z += w0 * v0.z + w1 * v1.z;
    acc.w += w0 * v0.w + w1 * v1.w;
  }
  if (e < end) {
    int s0 = csr_src[e];
    float w0 = csr_coef[e];
    float4 v0 = hw4[(size_t)s0 * 64 + lane];
    acc.x += w0 * v0.x;
    acc.y += w0 * v0.y;
    acc.z += w0 * v0.z;
    acc.w += w0 * v0.w;
  }
  float4 bb = ((const float4*)bias)[lane];
  acc.x += bb.x; acc.y += bb.y; acc.z += bb.z; acc.w += bb.w;
  acc.x = (acc.x > 0.f) ? acc.x : expm1f(acc.x);
  acc.y = (acc.y > 0.f) ? acc.y : expm1f(acc.y);
  acc.z = (acc.z > 0.f) ? acc.z : expm1f(acc.z);
  acc.w = (acc.w > 0.f) ? acc.w : expm1f(acc.w);
  ((float4*)out)[(size_t)n * 64 + lane] = acc;
}

// ---------------- pooling (batch is sorted -> range per graph) ----------------
__global__ __launch_bounds__(256) void find_start(const int* __restrict__ batch,
                                                  int* __restrict__ gstart) {
  int g = blockIdx.x * 256 + threadIdx.x;
  if (g <= NUM_GRAPHS) {
    int lo = 0, hi = N_NODES;
    while (lo < hi) {
      int mid = (lo + hi) >> 1;
      if (batch[mid] < g) lo = mid + 1; else hi = mid;
    }
    gstart[g] = lo;
  }
}

__global__ __launch_bounds__(256) void pool_mean(
    const float* __restrict__ h, const int* __restrict__ gstart,
    float* __restrict__ pooled) {
  int g = blockIdx.x;
  int f = threadIdx.x;
  int s = gstart[g], e = gstart[g + 1];
  float sum = 0.f;
  for (int n = s; n < e; ++n) sum += h[(size_t)n * HID + f];
  float denom = fmaxf((float)(e - s), 1.0f);
  pooled[(size_t)g * HID + f] = sum / denom;
}

__global__ __launch_bounds__(256) void final_lin(
    const float* __restrict__ pooled, const float* __restrict__ W,
    const float* __restrict__ b, float* __restrict__ out) {
  int g = blockIdx.x;
  __shared__ float part[NCLS * 256];
  int f = threadIdx.x;
  float v = pooled[(size_t)g * HID + f];
#pragma unroll
  for (int c = 0; c < NCLS; ++c) part[c * 256 + f] = v * W[f * NCLS + c];
  __syncthreads();
  for (int off = 128; off > 0; off >>= 1) {
    if (f < off) {
#pragma unroll
      for (int c = 0; c < NCLS; ++c) part[c * 256 + f] += part[c * 256 + f + off];
    }
    __syncthreads();
  }
  if (f < NCLS) out[g * NCLS + f] = part[f * 256] + b[f];
}

extern "C" void kernel_launch(void* const* d_in, const int* in_sizes, int n_in,
                              void* d_out, int out_size, void* d_ws, size_t ws_size,
                              hipStream_t stream) {
  const float* x = (const float*)d_in[0];
  const int* ei = (const int*)d_in[1];
  const int* e_src = ei;
  const int* e_dst = ei + N_EDGES;
  const float* ea = (const float*)d_in[2];
  // d_in[3] = edge_type: unused (edge_dim=1 mixing carries no per-type params)
  const int* batch = (const int*)d_in[4];
  const float* enc1_w = (const float*)d_in[5];
  const float* enc1_b = (const float*)d_in[6];
  const float* enc2_w = (const float*)d_in[7];
  const float* enc2_b = (const float*)d_in[8];
  const float* conv_ws = (const float*)d_in[9];
  const float* conv_bs = (const float*)d_in[10];
  const float* lin1_w = (const float*)d_in[11];
  const float* lin1_b = (const float*)d_in[12];
  float* out = (float*)d_out;

  char* w = (char*)d_ws;
  size_t off = 0;
  auto alloc = [&](size_t bytes) {
    size_t o = off;
    off = (off + bytes + 255) & ~(size_t)255;
    return (void*)(w + o);
  };
  float* bufA = (float*)alloc((size_t)N_NODES * HID * 4);
  float* bufB = (float*)alloc((size_t)N_NODES * HID * 4);
  float* deg = (float*)alloc((size_t)N_NODES * 4);
  float* dinv = (float*)alloc((size_t)N_NODES * 4);
  int* cnt = (int*)alloc((size_t)N_NODES * 4);
  int* row_ptr = (int*)alloc((size_t)(N_NODES + 1) * 4);
  int* cursor = (int*)alloc((size_t)N_NODES * 4);
  int* csr_src = (int*)alloc((size_t)N_EDGES * 4);
  float* csr_coef = (float*)alloc((size_t)N_EDGES * 4);
  float* pooled = (float*)alloc((size_t)NUM_GRAPHS * HID * 4);
  int* gstart = (int*)alloc((size_t)(NUM_GRAPHS + 1) * 4);
  (void)ws_size; (void)in_sizes; (void)n_in; (void)out_size;

  hipMemsetAsync(cnt, 0, (size_t)N_NODES * 4, stream);
  hipMemsetAsync(cursor, 0, (size_t)N_NODES * 4, stream);

  const int nb_nodes = (N_NODES + 255) / 256;
  const int nb_edges = (N_EDGES + 255) / 256;

  // graph normalization + CSR (independent of features; built once per call)
  deg_init<<<nb_nodes, 256, 0, stream>>>(deg, N_NODES);
  deg_accum<<<nb_edges, 256, 0, stream>>>(e_dst, ea, deg, cnt, N_EDGES);
  dinv_k<<<nb_nodes, 256, 0, stream>>>(deg, dinv, N_NODES);
  scan_excl<<<1, 1024, 0, stream>>>(cnt, row_ptr, N_NODES);
  csr_fill<<<nb_edges, 256, 0, stream>>>(e_src, e_dst, ea, dinv, row_ptr, cursor,
                                         csr_src, csr_coef, N_EDGES);
  find_start<<<(NUM_GRAPHS + 256) / 256, 256, 0, stream>>>(batch, gstart);

  const int gR = (N_NODES + TBM - 1) / TBM;  // 391

  // encoder: h0 = x@enc1_w + b (N,128) -> bufB ; h1 = h0@enc2_w + b (N,256) -> bufA
  {
    dim3 grid(gR, F_IN / TBN);
    gemm_bias<<<grid, 256, 0, stream>>>(x, enc1_w, enc1_b, bufB, N_NODES, F_IN, F_IN);
  }
  {
    dim3 grid(gR, HID / TBN);
    gemm_bias<<<grid, 256, 0, stream>>>(bufB, enc2_w, enc2_b, bufA, N_NODES, F_IN, HID);
  }

  // 4 GCN layers: hW = h@W (bufA->bufB); aggregate+bias+ELU (bufB->bufA)
  for (int layer = 0; layer < 4; ++layer) {
    dim3 grid(gR, HID / TBN);
    gemm_bias<<<grid, 256, 0, stream>>>(bufA, conv_ws + (size_t)layer * HID * HID,
                                        nullptr, bufB, N_NODES, HID, HID);
    gather_elu<<<(N_NODES + 3) / 4, 256, 0, stream>>>(
        bufB, dinv, row_ptr, csr_src, csr_coef,
        conv_bs + (size_t)layer * HID, bufA);
  }

  // deterministic mean-pool per graph + final linear
  pool_mean<<<NUM_GRAPHS, 256, 0, stream>>>(bufA, gstart, pooled);
  final_lin<<<NUM_GRAPHS, 256, 0, stream>>>(pooled, lin1_w, lin1_b, out);
}

// Round 3
// 1171.393 us; speedup vs baseline: 1.1897x; 1.0592x over previous
//
#include <hip/hip_runtime.h>
#include <hip/hip_bf16.h>
#include <math.h>

#define N_NODES 50000
#define N_EDGES 800000
#define NUM_GRAPHS 500
#define F_IN 128
#define HID 256
#define NCLS 10

// ---------------- GEMM: C[N,M] = A[N,K] @ B[K,M] (+ bias) ----------------
// 128x128 tile, BK=16, 256 threads, 8x8 accum per thread, float4 LDS traffic.
#define TBM 128
#define TBN 128
#define TBK 16

__global__ __launch_bounds__(256) void gemm_bias(
    const float* __restrict__ A, const float* __restrict__ B,
    const float* __restrict__ bias, float* __restrict__ C,
    int N, int K, int M) {
  __shared__ float As[TBK][TBM + 4];  // transposed A tile; +4 keeps 16B align
  __shared__ float Bs[TBK][TBN];
  const int row0 = blockIdx.x * TBM;
  const int col0 = blockIdx.y * TBN;
  const int t = threadIdx.x;
  const int tx = t & 15, ty = t >> 4;
  float acc[8][8] = {};
  for (int k0 = 0; k0 < K; k0 += TBK) {
#pragma unroll
    for (int i = 0; i < 2; ++i) {
      int idx = t + i * 256;
      int row = idx >> 2;
      int kv = (idx & 3) * 4;
      int gr = row0 + row;
      float4 v = make_float4(0.f, 0.f, 0.f, 0.f);
      if (gr < N) v = *(const float4*)(A + (size_t)gr * K + k0 + kv);
      As[kv + 0][row] = v.x;
      As[kv + 1][row] = v.y;
      As[kv + 2][row] = v.z;
      As[kv + 3][row] = v.w;
    }
#pragma unroll
    for (int i = 0; i < 2; ++i) {
      int idx = t + i * 256;
      int k = idx >> 5;
      int c = (idx & 31) * 4;
      *(float4*)&Bs[k][c] = *(const float4*)(B + (size_t)(k0 + k) * M + col0 + c);
    }
    __syncthreads();
#pragma unroll
    for (int k = 0; k < TBK; ++k) {
      float a[8], b[8];
      *(float4*)&a[0] = *(const float4*)&As[k][ty * 4];
      *(float4*)&a[4] = *(const float4*)&As[k][ty * 4 + 64];
      *(float4*)&b[0] = *(const float4*)&Bs[k][tx * 4];
      *(float4*)&b[4] = *(const float4*)&Bs[k][tx * 4 + 64];
#pragma unroll
      for (int i = 0; i < 8; ++i)
#pragma unroll
        for (int j = 0; j < 8; ++j) acc[i][j] += a[i] * b[j];
    }
    __syncthreads();
  }
#pragma unroll
  for (int ih = 0; ih < 2; ++ih) {
#pragma unroll
    for (int i = 0; i < 4; ++i) {
      int gr = row0 + ih * 64 + ty * 4 + i;
      if (gr < N) {
#pragma unroll
        for (int jh = 0; jh < 2; ++jh) {
          int gc = col0 + jh * 64 + tx * 4;
          float4 v;
          v.x = acc[ih * 4 + i][jh * 4 + 0];
          v.y = acc[ih * 4 + i][jh * 4 + 1];
          v.z = acc[ih * 4 + i][jh * 4 + 2];
          v.w = acc[ih * 4 + i][jh * 4 + 3];
          if (bias) {
            v.x += bias[gc + 0];
            v.y += bias[gc + 1];
            v.z += bias[gc + 2];
            v.w += bias[gc + 3];
          }
          *(float4*)(C + (size_t)gr * M + gc) = v;
        }
      }
    }
  }
}

// ---------------- degree / normalization ----------------
__global__ __launch_bounds__(256) void deg_init(float* deg, int N) {
  int i = blockIdx.x * 256 + threadIdx.x;
  if (i < N) deg[i] = 1.0f;  // self-loop weight
}

__global__ __launch_bounds__(256) void deg_accum(
    const int* __restrict__ dst, const float* __restrict__ ew,
    float* deg, int* cnt, int E) {
  int e = blockIdx.x * 256 + threadIdx.x;
  if (e < E) {
    int d = dst[e];
    atomicAdd(&deg[d], ew[e]);
    atomicAdd(&cnt[d], 1);
  }
}

__global__ __launch_bounds__(256) void dinv_k(const float* deg, float* dinv, int N) {
  int i = blockIdx.x * 256 + threadIdx.x;
  if (i < N) {
    float d = deg[i];
    dinv[i] = (d > 0.f) ? rsqrtf(fmaxf(d, 1e-12f)) : 0.f;
  }
}

// ---------------- hierarchical exclusive scan (3 kernels) ----------------
// phase 1: per-256-block sums
__global__ __launch_bounds__(256) void scan_p1(const int* __restrict__ cnt,
                                               int* __restrict__ bsum, int n) {
  __shared__ int s[256];
  int i = blockIdx.x * 256 + threadIdx.x;
  s[threadIdx.x] = (i < n) ? cnt[i] : 0;
  __syncthreads();
  for (int off = 128; off > 0; off >>= 1) {
    if (threadIdx.x < off) s[threadIdx.x] += s[threadIdx.x + off];
    __syncthreads();
  }
  if (threadIdx.x == 0) bsum[blockIdx.x] = s[0];
}

// phase 2: single block exclusive-scan of nb block sums (nb <= 256); also
// writes grand total to *total_out.
__global__ __launch_bounds__(256) void scan_p2(int* __restrict__ bsum, int nb,
                                               int* __restrict__ total_out) {
  __shared__ int s[256];
  int t = threadIdx.x;
  int v = (t < nb) ? bsum[t] : 0;
  s[t] = v;
  __syncthreads();
  for (int off = 1; off < 256; off <<= 1) {
    int u = (t >= off) ? s[t - off] : 0;
    __syncthreads();
    s[t] += u;
    __syncthreads();
  }
  if (t < nb) bsum[t] = s[t] - v;  // exclusive
  if (t == 255) *total_out = s[255];
}

// phase 3: row_ptr[i] = bsum_excl[blk] + exclusive_scan_within_block(cnt)[i]
__global__ __launch_bounds__(256) void scan_p3(const int* __restrict__ cnt,
                                               const int* __restrict__ bsum,
                                               int* __restrict__ row_ptr, int n) {
  __shared__ int s[256];
  int i = blockIdx.x * 256 + threadIdx.x;
  int t = threadIdx.x;
  int v = (i < n) ? cnt[i] : 0;
  s[t] = v;
  __syncthreads();
  for (int off = 1; off < 256; off <<= 1) {
    int u = (t >= off) ? s[t - off] : 0;
    __syncthreads();
    s[t] += u;
    __syncthreads();
  }
  if (i < n) row_ptr[i] = bsum[blockIdx.x] + s[t] - v;
}

// ---------------- CSR fill: (src, coef) packed as int2 ----------------
__global__ __launch_bounds__(256) void csr_fill(
    const int* __restrict__ src, const int* __restrict__ dst,
    const float* __restrict__ ew, const float* __restrict__ dinv,
    const int* __restrict__ row_ptr, int* cursor,
    int2* __restrict__ csr_ent, int E) {
  int e = blockIdx.x * 256 + threadIdx.x;
  if (e < E) {
    int s = src[e], d = dst[e];
    int pos = atomicAdd(&cursor[d], 1);
    int idx = row_ptr[d] + pos;
    float coef = dinv[s] * ew[e] * dinv[d];
    csr_ent[idx] = make_int2(s, __float_as_int(coef));
  }
}

// ---------------- aggregation + bias + ELU: one wave per node ----------------
__global__ __launch_bounds__(256) void gather_elu(
    const float* __restrict__ hW, const float* __restrict__ dinv,
    const int* __restrict__ row_ptr, const int2* __restrict__ csr_ent,
    const float* __restrict__ bias, float* __restrict__ out) {
  const int wave = threadIdx.x >> 6;
  const int lane = threadIdx.x & 63;
  const int n = blockIdx.x * 4 + wave;
  if (n >= N_NODES) return;
  const float4* hw4 = (const float4*)hW;  // 64 float4 per row
  const int start = row_ptr[n], end = row_ptr[n + 1];
  const float di = dinv[n];
  const float cself = di * di;
  float4 h = hw4[(size_t)n * 64 + lane];
  float4 acc0, acc1;
  acc0.x = cself * h.x; acc0.y = cself * h.y;
  acc0.z = cself * h.z; acc0.w = cself * h.w;
  acc1.x = 0.f; acc1.y = 0.f; acc1.z = 0.f; acc1.w = 0.f;
  int e = start;
  for (; e + 4 <= end; e += 4) {
    int2 e0 = csr_ent[e], e1 = csr_ent[e + 1];
    int2 e2 = csr_ent[e + 2], e3 = csr_ent[e + 3];
    float4 v0 = hw4[(size_t)e0.x * 64 + lane];
    float4 v1 = hw4[(size_t)e1.x * 64 + lane];
    float4 v2 = hw4[(size_t)e2.x * 64 + lane];
    float4 v3 = hw4[(size_t)e3.x * 64 + lane];
    float w0 = __int_as_float(e0.y), w1 = __int_as_float(e1.y);
    float w2 = __int_as_float(e2.y), w3 = __int_as_float(e3.y);
    acc0.x += w0 * v0.x + w2 * v2.x;
    acc0.y += w0 * v0.y + w2 * v2.y;
    acc0.z += w0 * v0.z + w2 * v2.z;
    acc0.w += w0 * v0.w + w2 * v2.w;
    acc1.x += w1 * v1.x + w3 * v3.x;
    acc1.y += w1 * v1.y + w3 * v3.y;
    acc1.z += w1 * v1.z + w3 * v3.z;
    acc1.w += w1 * v1.w + w3 * v3.w;
  }
  for (; e < end; ++e) {
    int2 e0 = csr_ent[e];
    float w0 = __int_as_float(e0.y);
    float4 v0 = hw4[(size_t)e0.x * 64 + lane];
    acc0.x += w0 * v0.x;
    acc0.y += w0 * v0.y;
    acc0.z += w0 * v0.z;
    acc0.w += w0 * v0.w;
  }
  float4 bb = ((const float4*)bias)[lane];
  acc0.x += acc1.x + bb.x;
  acc0.y += acc1.y + bb.y;
  acc0.z += acc1.z + bb.z;
  acc0.w += acc1.w + bb.w;
  acc0.x = (acc0.x > 0.f) ? acc0.x : expm1f(acc0.x);
  acc0.y = (acc0.y > 0.f) ? acc0.y : expm1f(acc0.y);
  acc0.z = (acc0.z > 0.f) ? acc0.z : expm1f(acc0.z);
  acc0.w = (acc0.w > 0.f) ? acc0.w : expm1f(acc0.w);
  ((float4*)out)[(size_t)n * 64 + lane] = acc0;
}

// ---------------- pooling (batch is sorted -> range per graph) ----------------
__global__ __launch_bounds__(256) void find_start(const int* __restrict__ batch,
                                                  int* __restrict__ gstart) {
  int g = blockIdx.x * 256 + threadIdx.x;
  if (g <= NUM_GRAPHS) {
    int lo = 0, hi = N_NODES;
    while (lo < hi) {
      int mid = (lo + hi) >> 1;
      if (batch[mid] < g) lo = mid + 1; else hi = mid;
    }
    gstart[g] = lo;
  }
}

__global__ __launch_bounds__(256) void pool_mean(
    const float* __restrict__ h, const int* __restrict__ gstart,
    float* __restrict__ pooled) {
  int g = blockIdx.x;
  int f = threadIdx.x;
  int s = gstart[g], e = gstart[g + 1];
  float sum = 0.f;
  for (int n = s; n < e; ++n) sum += h[(size_t)n * HID + f];
  float denom = fmaxf((float)(e - s), 1.0f);
  pooled[(size_t)g * HID + f] = sum / denom;
}

__global__ __launch_bounds__(256) void final_lin(
    const float* __restrict__ pooled, const float* __restrict__ W,
    const float* __restrict__ b, float* __restrict__ out) {
  int g = blockIdx.x;
  __shared__ float part[NCLS * 256];
  int f = threadIdx.x;
  float v = pooled[(size_t)g * HID + f];
#pragma unroll
  for (int c = 0; c < NCLS; ++c) part[c * 256 + f] = v * W[f * NCLS + c];
  __syncthreads();
  for (int off = 128; off > 0; off >>= 1) {
    if (f < off) {
#pragma unroll
      for (int c = 0; c < NCLS; ++c) part[c * 256 + f] += part[c * 256 + f + off];
    }
    __syncthreads();
  }
  if (f < NCLS) out[g * NCLS + f] = part[f * 256] + b[f];
}

extern "C" void kernel_launch(void* const* d_in, const int* in_sizes, int n_in,
                              void* d_out, int out_size, void* d_ws, size_t ws_size,
                              hipStream_t stream) {
  const float* x = (const float*)d_in[0];
  const int* ei = (const int*)d_in[1];
  const int* e_src = ei;
  const int* e_dst = ei + N_EDGES;
  const float* ea = (const float*)d_in[2];
  // d_in[3] = edge_type: unused (edge_dim=1 mixing carries no per-type params)
  const int* batch = (const int*)d_in[4];
  const float* enc1_w = (const float*)d_in[5];
  const float* enc1_b = (const float*)d_in[6];
  const float* enc2_w = (const float*)d_in[7];
  const float* enc2_b = (const float*)d_in[8];
  const float* conv_ws = (const float*)d_in[9];
  const float* conv_bs = (const float*)d_in[10];
  const float* lin1_w = (const float*)d_in[11];
  const float* lin1_b = (const float*)d_in[12];
  float* out = (float*)d_out;

  char* w = (char*)d_ws;
  size_t off = 0;
  auto alloc = [&](size_t bytes) {
    size_t o = off;
    off = (off + bytes + 255) & ~(size_t)255;
    return (void*)(w + o);
  };
  float* bufA = (float*)alloc((size_t)N_NODES * HID * 4);
  float* bufB = (float*)alloc((size_t)N_NODES * HID * 4);
  float* deg = (float*)alloc((size_t)N_NODES * 4);
  float* dinv = (float*)alloc((size_t)N_NODES * 4);
  int* cnt = (int*)alloc((size_t)N_NODES * 4);
  int* row_ptr = (int*)alloc((size_t)(N_NODES + 1) * 4);
  int* cursor = (int*)alloc((size_t)N_NODES * 4);
  int* bsum = (int*)alloc((size_t)256 * 4);
  int2* csr_ent = (int2*)alloc((size_t)N_EDGES * 8);
  float* pooled = (float*)alloc((size_t)NUM_GRAPHS * HID * 4);
  int* gstart = (int*)alloc((size_t)(NUM_GRAPHS + 1) * 4);
  (void)ws_size; (void)in_sizes; (void)n_in; (void)out_size;

  hipMemsetAsync(cnt, 0, (size_t)N_NODES * 4, stream);
  hipMemsetAsync(cursor, 0, (size_t)N_NODES * 4, stream);

  const int nb_nodes = (N_NODES + 255) / 256;  // 196
  const int nb_edges = (N_EDGES + 255) / 256;

  // graph normalization + CSR (independent of features; built once per call)
  deg_init<<<nb_nodes, 256, 0, stream>>>(deg, N_NODES);
  deg_accum<<<nb_edges, 256, 0, stream>>>(e_dst, ea, deg, cnt, N_EDGES);
  dinv_k<<<nb_nodes, 256, 0, stream>>>(deg, dinv, N_NODES);
  scan_p1<<<nb_nodes, 256, 0, stream>>>(cnt, bsum, N_NODES);
  scan_p2<<<1, 256, 0, stream>>>(bsum, nb_nodes, row_ptr + N_NODES);
  scan_p3<<<nb_nodes, 256, 0, stream>>>(cnt, bsum, row_ptr, N_NODES);
  csr_fill<<<nb_edges, 256, 0, stream>>>(e_src, e_dst, ea, dinv, row_ptr, cursor,
                                         csr_ent, N_EDGES);
  find_start<<<(NUM_GRAPHS + 256) / 256, 256, 0, stream>>>(batch, gstart);

  const int gR = (N_NODES + TBM - 1) / TBM;  // 391

  // encoder: h0 = x@enc1_w + b (N,128) -> bufB ; h1 = h0@enc2_w + b (N,256) -> bufA
  {
    dim3 grid(gR, F_IN / TBN);
    gemm_bias<<<grid, 256, 0, stream>>>(x, enc1_w, enc1_b, bufB, N_NODES, F_IN, F_IN);
  }
  {
    dim3 grid(gR, HID / TBN);
    gemm_bias<<<grid, 256, 0, stream>>>(bufB, enc2_w, enc2_b, bufA, N_NODES, F_IN, HID);
  }

  // 4 GCN layers: hW = h@W (bufA->bufB); aggregate+bias+ELU (bufB->bufA)
  for (int layer = 0; layer < 4; ++layer) {
    dim3 grid(gR, HID / TBN);
    gemm_bias<<<grid, 256, 0, stream>>>(bufA, conv_ws + (size_t)layer * HID * HID,
                                        nullptr, bufB, N_NODES, HID, HID);
    gather_elu<<<(N_NODES + 3) / 4, 256, 0, stream>>>(
        bufB, dinv, row_ptr, csr_ent,
        conv_bs + (size_t)layer * HID, bufA);
  }

  // deterministic mean-pool per graph + final linear
  pool_mean<<<NUM_GRAPHS, 256, 0, stream>>>(bufA, gstart, pooled);
  final_lin<<<NUM_GRAPHS, 256, 0, stream>>>(pooled, lin1_w, lin1_b, out);
}